// Round 4
// baseline (189.424 us; speedup 1.0000x reference)
//
#include <hip/hip_runtime.h>
#include <hip/hip_bf16.h>

// Fused recurrent net, 16x16x32 MFMA, 16 rows/wave, ZERO LDS.
// All matmuls as C^T = W * act^T (col = batch row = lane&15 everywhere).
// Hot-loop weights (WI2E, WE2I) live in VGPRs for the whole kernel; the
// C/D -> next-B remap is in-register via permlane32_swap + permlane16_swap.
// Win2E / WE2Out stream from global (L2-resident) in the once-per-wave
// ff / out phases.

typedef __bf16 bf16x8_t __attribute__((ext_vector_type(8)));
typedef float f32x4_t __attribute__((ext_vector_type(4)));
typedef unsigned int uintx4_t __attribute__((ext_vector_type(4)));

#define THREADS 256

__device__ __forceinline__ f32x4_t mfma16(bf16x8_t a, bf16x8_t b, f32x4_t c) {
  return __builtin_amdgcn_mfma_f32_16x16x32_bf16(a, b, c, 0, 0, 0);
}

// x[32+i] <-> y[i]: x gathers both low halves, y both high halves.
__device__ __forceinline__ void swap32(unsigned int& x, unsigned int& y) {
  asm("v_permlane32_swap_b32 %0, %1" : "+v"(x), "+v"(y));
}
// x[16+i] <-> y[i] within each 32-lane half.
__device__ __forceinline__ void swap16(unsigned int& x, unsigned int& y) {
  asm("v_permlane16_swap_b32 %0, %1" : "+v"(x), "+v"(y));
}

__device__ __forceinline__ unsigned int pack2_relu(float a, float b) {
  unsigned short lo = __builtin_bit_cast(unsigned short, (__bf16)fmaxf(a, 0.f));
  unsigned short hi = __builtin_bit_cast(unsigned short, (__bf16)fmaxf(b, 0.f));
  return (unsigned int)lo | ((unsigned int)hi << 16);
}

// Build one B-frag (one 32-wide k-step) from two 16x16 C/D tiles
// (t0 = features f..f+15, t1 = features f+16..f+31), relu applied.
// C/D: col=lane&15, row=(lane>>4)*4+reg.  B-frag: col=lane&15,
// k=(lane>>4)*8+j.  Routing: swap32 then swap16 on packed dword pairs;
// the swap byproduct is exactly the second needed word.
__device__ __forceinline__ bf16x8_t remap2(const f32x4_t& t0,
                                           const f32x4_t& t1) {
  unsigned int A0 = pack2_relu(t0[0], t0[1]);
  unsigned int A1 = pack2_relu(t0[2], t0[3]);
  unsigned int B0 = pack2_relu(t1[0], t1[1]);
  unsigned int B1 = pack2_relu(t1[2], t1[3]);
  swap32(A0, B0);
  swap16(A0, B0);  // A0 = w0, B0 = w2
  swap32(A1, B1);
  swap16(A1, B1);  // A1 = w1, B1 = w3
  return __builtin_bit_cast(bf16x8_t, (uintx4_t){A0, A1, B0, B1});
}

__device__ __forceinline__ bf16x8_t cvt8(float4 v0, float4 v1) {
  bf16x8_t h;
  h[0] = (__bf16)v0.x; h[1] = (__bf16)v0.y;
  h[2] = (__bf16)v0.z; h[3] = (__bf16)v0.w;
  h[4] = (__bf16)v1.x; h[5] = (__bf16)v1.y;
  h[6] = (__bf16)v1.z; h[7] = (__bf16)v1.w;
  return h;
}

// A-frag from row-major fp32 W[ROWS][COLS]: lane holds
// W[mt*16 + (lane&15)][s*32 + (lane>>4)*8 + j], j=0..7.
__device__ __forceinline__ bf16x8_t gfrag(const float* __restrict__ W,
                                          int off) {
  float4 v0 = *reinterpret_cast<const float4*>(W + off);
  float4 v1 = *reinterpret_cast<const float4*>(W + off + 4);
  return cvt8(v0, v1);
}

__global__ __launch_bounds__(THREADS, 2) void unet_fused(
    const float* __restrict__ x,
    const float* __restrict__ Win2E,
    const float* __restrict__ WI2E,
    const float* __restrict__ WE2I,
    const float* __restrict__ WE2Out,
    const int* __restrict__ Tptr,
    float* __restrict__ out) {
  const int tid = threadIdx.x;
  const int wid = tid >> 6, lane = tid & 63;
  const int c = lane & 15, q = lane >> 4;
  const int T = *Tptr;
  const long row0 = ((long)blockIdx.x * 4 + wid) * 16;
  const f32x4_t Z = {};

  // x B-frags: issue the HBM loads first (hide under weight hoisting).
  const float* xrow = x + (row0 + c) * 128 + q * 8;
  float4 xv[8];
#pragma unroll
  for (int s = 0; s < 4; ++s) {
    xv[2 * s] = *reinterpret_cast<const float4*>(xrow + s * 32);
    xv[2 * s + 1] = *reinterpret_cast<const float4*>(xrow + s * 32 + 4);
  }

  // Hoist hot-loop weights into registers (reads hit L2: 192 KB total).
  // WI2E: [128][64] -> A-frags mt 0..7, s 0..1.
  bf16x8_t wi2e[8][2];
#pragma unroll
  for (int mt = 0; mt < 8; ++mt)
#pragma unroll
    for (int s = 0; s < 2; ++s)
      wi2e[mt][s] = gfrag(WI2E, (mt * 16 + c) * 64 + s * 32 + q * 8);
  // WE2I: [64][128] -> A-frags mt 0..3, s 0..3.
  bf16x8_t we2i[4][4];
#pragma unroll
  for (int mt = 0; mt < 4; ++mt)
#pragma unroll
    for (int s = 0; s < 4; ++s)
      we2i[mt][s] = gfrag(WE2I, (mt * 16 + c) * 128 + s * 32 + q * 8);

  bf16x8_t xb[4];
#pragma unroll
  for (int s = 0; s < 4; ++s) xb[s] = cvt8(xv[2 * s], xv[2 * s + 1]);

  // ff^T = Win2E * x^T (Win2E frags streamed from L2), f32 for whole kernel.
  f32x4_t ff[8];
#pragma unroll
  for (int mt = 0; mt < 8; ++mt)
    ff[mt] = mfma16(gfrag(Win2E, (mt * 16 + c) * 128 + q * 8), xb[0], Z);
#pragma unroll
  for (int s = 1; s < 4; ++s)
#pragma unroll
    for (int mt = 0; mt < 8; ++mt)
      ff[mt] = mfma16(gfrag(Win2E, (mt * 16 + c) * 128 + s * 32 + q * 8),
                      xb[s], ff[mt]);

  f32x4_t acc_e[8];
#pragma unroll
  for (int mt = 0; mt < 8; ++mt) acc_e[mt] = ff[mt];  // step 0: actI = 0

  // T-1 full steps; the t-loop touches no memory at all.
  for (int t = 0; t < T - 1; ++t) {
    // actI^T = relu-free accum of WE2I * relu(acc_e)^T
    f32x4_t acc_i[4];
#pragma unroll
    for (int s = 0; s < 4; ++s) {
      bf16x8_t ebs = remap2(acc_e[2 * s], acc_e[2 * s + 1]);
#pragma unroll
      for (int mt = 0; mt < 4; ++mt)
        acc_i[mt] = mfma16(we2i[mt][s], ebs, s == 0 ? Z : acc_i[mt]);
    }
    // acc_e = ff + WI2E * relu(acc_i)^T
#pragma unroll
    for (int s = 0; s < 2; ++s) {
      bf16x8_t ibs = remap2(acc_i[2 * s], acc_i[2 * s + 1]);
#pragma unroll
      for (int mt = 0; mt < 8; ++mt)
        acc_e[mt] = mfma16(wi2e[mt][s], ibs, s == 0 ? ff[mt] : acc_e[mt]);
    }
  }

  // out^T = relu(WE2Out * relu(acc_e)^T), WE2Out frags streamed from L2.
  bf16x8_t eb[4];
#pragma unroll
  for (int s = 0; s < 4; ++s)
    eb[s] = remap2(acc_e[2 * s], acc_e[2 * s + 1]);
#pragma unroll
  for (int mt = 0; mt < 8; ++mt) {
    f32x4_t o = mfma16(gfrag(WE2Out, (mt * 16 + c) * 128 + q * 8), eb[0], Z);
#pragma unroll
    for (int s = 1; s < 4; ++s)
      o = mfma16(gfrag(WE2Out, (mt * 16 + c) * 128 + s * 32 + q * 8), eb[s], o);
    f32x4_t r;
#pragma unroll
    for (int j = 0; j < 4; ++j) r[j] = fmaxf(o[j], 0.f);
    *reinterpret_cast<f32x4_t*>(out + (row0 + c) * 128 + mt * 16 + q * 4) = r;
  }
}

extern "C" void kernel_launch(void* const* d_in, const int* in_sizes, int n_in,
                              void* d_out, int out_size, void* d_ws,
                              size_t ws_size, hipStream_t stream) {
  const float* x = (const float*)d_in[0];
  const float* Win2E = (const float*)d_in[1];
  const float* WI2E = (const float*)d_in[2];
  const float* WE2I = (const float*)d_in[3];
  const float* WE2Out = (const float*)d_in[4];
  const int* Tptr = (const int*)d_in[5];
  float* out = (float*)d_out;
  (void)n_in; (void)out_size; (void)d_ws; (void)ws_size;

  const int B = in_sizes[0] / 128;  // 131072
  dim3 grid(B / 64), block(THREADS);
  unet_fused<<<grid, block, 0, stream>>>(x, Win2E, WI2E, WE2I, WE2Out, Tptr,
                                         out);
}

// Round 5
// 145.073 us; speedup vs baseline: 1.3057x; 1.3057x over previous
//
#include <hip/hip_runtime.h>
#include <hip/hip_bf16.h>

// Fused recurrent net, 16x16x32 MFMA, 16 rows/wave.
// All matmuls as C^T = W * act^T (col = batch row = lane&15 everywhere).
// - Activations: register-resident; C/D -> B-frag remap via
//   v_permlane32_swap_b32 + v_permlane16_swap_b32 (verified R4).
// - Hot-loop weights (WI2E, WE2I): frag-packed bf16 LDS, conflict-free
//   (verified R2), 32 KB/block -> 2 blocks/CU.
// - Cold weights (Win2E, WE2Out): streamed from L2 once per wave.
// - __launch_bounds__(512,4): cap 128 VGPR -> 4 waves/SIMD (2x R1 TLP).

typedef __bf16 bf16x8_t __attribute__((ext_vector_type(8)));
typedef float f32x4_t __attribute__((ext_vector_type(4)));
typedef unsigned int uintx4_t __attribute__((ext_vector_type(4)));

#define THREADS 512

// Frag-packed bf16 LDS: frag fi for lane l at (fi*64 + l)*16 bytes.
#define OFF_WI2E 0       // 8mt x 2ks = 16 frags -> 16 KB
#define OFF_WE2I 16384   // 4mt x 4ks = 16 frags -> 16 KB
#define SMEM_TOTAL 32768

__device__ __forceinline__ f32x4_t mfma16(bf16x8_t a, bf16x8_t b, f32x4_t c) {
  return __builtin_amdgcn_mfma_f32_16x16x32_bf16(a, b, c, 0, 0, 0);
}

__device__ __forceinline__ void swap32(unsigned int& x, unsigned int& y) {
  asm("v_permlane32_swap_b32 %0, %1" : "+v"(x), "+v"(y));
}
__device__ __forceinline__ void swap16(unsigned int& x, unsigned int& y) {
  asm("v_permlane16_swap_b32 %0, %1" : "+v"(x), "+v"(y));
}

__device__ __forceinline__ unsigned int pack2_relu(float a, float b) {
  unsigned short lo = __builtin_bit_cast(unsigned short, (__bf16)fmaxf(a, 0.f));
  unsigned short hi = __builtin_bit_cast(unsigned short, (__bf16)fmaxf(b, 0.f));
  return (unsigned int)lo | ((unsigned int)hi << 16);
}

// Two 16x16 C/D tiles (features f..f+15, f+16..f+31) -> one B-frag for the
// 32-wide k-step, relu applied.  Verified in R4 (absmax 9.8e-4).
__device__ __forceinline__ bf16x8_t remap2(const f32x4_t& t0,
                                           const f32x4_t& t1) {
  unsigned int A0 = pack2_relu(t0[0], t0[1]);
  unsigned int A1 = pack2_relu(t0[2], t0[3]);
  unsigned int B0 = pack2_relu(t1[0], t1[1]);
  unsigned int B1 = pack2_relu(t1[2], t1[3]);
  swap32(A0, B0);
  swap16(A0, B0);
  swap32(A1, B1);
  swap16(A1, B1);
  return __builtin_bit_cast(bf16x8_t, (uintx4_t){A0, A1, B0, B1});
}

__device__ __forceinline__ bf16x8_t cvt8(float4 v0, float4 v1) {
  bf16x8_t h;
  h[0] = (__bf16)v0.x; h[1] = (__bf16)v0.y;
  h[2] = (__bf16)v0.z; h[3] = (__bf16)v0.w;
  h[4] = (__bf16)v1.x; h[5] = (__bf16)v1.y;
  h[6] = (__bf16)v1.z; h[7] = (__bf16)v1.w;
  return h;
}

// A-frag streamed from row-major fp32 W: lane holds
// W[mt*16 + (lane&15)][s*32 + (lane>>4)*8 + j], j=0..7.
__device__ __forceinline__ bf16x8_t gfrag(const float* __restrict__ W,
                                          int off) {
  float4 v0 = *reinterpret_cast<const float4*>(W + off);
  float4 v1 = *reinterpret_cast<const float4*>(W + off + 4);
  return cvt8(v0, v1);
}

__device__ __forceinline__ bf16x8_t ldsfrag(const char* smem, int off, int fi,
                                            int lane) {
  return *reinterpret_cast<const bf16x8_t*>(smem + off + (fi * 64 + lane) * 16);
}

// Stage one weight matrix into frag-packed bf16 LDS (conflict-free).
template <int NMT, int NKS, int COLS>
__device__ __forceinline__ void stage_frags(const float* __restrict__ W,
                                            char* dst, int tid) {
  constexpr int SLOTS = NMT * NKS * 64;
#pragma unroll
  for (int it = 0; it < SLOTS / THREADS; ++it) {
    int slot = it * THREADS + tid;
    int lane = slot & 63;
    int fi = slot >> 6;
    int mt = fi / NKS, ks = fi % NKS;
    int cc = lane & 15, hh = lane >> 4;
    const float* src = W + (mt * 16 + cc) * COLS + ks * 32 + hh * 8;
    float4 v0 = *reinterpret_cast<const float4*>(src);
    float4 v1 = *reinterpret_cast<const float4*>(src + 4);
    *reinterpret_cast<bf16x8_t*>(dst + slot * 16) = cvt8(v0, v1);
  }
}

__global__ __launch_bounds__(THREADS, 4) void unet_fused(
    const float* __restrict__ x,
    const float* __restrict__ Win2E,
    const float* __restrict__ WI2E,
    const float* __restrict__ WE2I,
    const float* __restrict__ WE2Out,
    const int* __restrict__ Tptr,
    float* __restrict__ out) {
  __shared__ __align__(16) char smem[SMEM_TOTAL];
  const int tid = threadIdx.x;

  stage_frags<8, 2, 64>(WI2E, smem + OFF_WI2E, tid);
  stage_frags<4, 4, 128>(WE2I, smem + OFF_WE2I, tid);

  const int wid = tid >> 6, lane = tid & 63;
  const int c = lane & 15, q = lane >> 4;
  const int T = *Tptr;
  const long row0 = ((long)blockIdx.x * 8 + wid) * 16;
  const f32x4_t Z = {};

  // x loads (HBM/L3) issued before the barrier to hide latency.
  const float* xrow = x + (row0 + c) * 128 + q * 8;
  float4 xv[8];
#pragma unroll
  for (int s = 0; s < 4; ++s) {
    xv[2 * s] = *reinterpret_cast<const float4*>(xrow + s * 32);
    xv[2 * s + 1] = *reinterpret_cast<const float4*>(xrow + s * 32 + 4);
  }
  bf16x8_t xb[4];
#pragma unroll
  for (int s = 0; s < 4; ++s) xb[s] = cvt8(xv[2 * s], xv[2 * s + 1]);

  __syncthreads();

  // ff^T = Win2E * x^T (Win2E streamed from L2), f32 for the whole kernel.
  f32x4_t ff[8];
#pragma unroll
  for (int mt = 0; mt < 8; ++mt)
    ff[mt] = mfma16(gfrag(Win2E, (mt * 16 + c) * 128 + q * 8), xb[0], Z);
#pragma unroll
  for (int s = 1; s < 4; ++s)
#pragma unroll
    for (int mt = 0; mt < 8; ++mt)
      ff[mt] = mfma16(gfrag(Win2E, (mt * 16 + c) * 128 + s * 32 + q * 8),
                      xb[s], ff[mt]);

  f32x4_t acc_e[8];
#pragma unroll
  for (int mt = 0; mt < 8; ++mt) acc_e[mt] = ff[mt];  // step 0: actI = 0

  // T-1 full steps; weights via conflict-free ds_read_b128, acts in regs.
  for (int t = 0; t < T - 1; ++t) {
    f32x4_t acc_i[4];
#pragma unroll
    for (int s = 0; s < 4; ++s) {
      bf16x8_t ebs = remap2(acc_e[2 * s], acc_e[2 * s + 1]);
#pragma unroll
      for (int mt = 0; mt < 4; ++mt)
        acc_i[mt] = mfma16(ldsfrag(smem, OFF_WE2I, mt * 4 + s, lane), ebs,
                           s == 0 ? Z : acc_i[mt]);
    }
#pragma unroll
    for (int s = 0; s < 2; ++s) {
      bf16x8_t ibs = remap2(acc_i[2 * s], acc_i[2 * s + 1]);
#pragma unroll
      for (int mt = 0; mt < 8; ++mt)
        acc_e[mt] = mfma16(ldsfrag(smem, OFF_WI2E, mt * 2 + s, lane), ibs,
                           s == 0 ? ff[mt] : acc_e[mt]);
    }
  }

  // out^T = relu(WE2Out * relu(acc_e)^T), WE2Out streamed from L2.
  bf16x8_t eb[4];
#pragma unroll
  for (int s = 0; s < 4; ++s) eb[s] = remap2(acc_e[2 * s], acc_e[2 * s + 1]);
#pragma unroll
  for (int mt = 0; mt < 8; ++mt) {
    f32x4_t o = mfma16(gfrag(WE2Out, (mt * 16 + c) * 128 + q * 8), eb[0], Z);
#pragma unroll
    for (int s = 1; s < 4; ++s)
      o = mfma16(gfrag(WE2Out, (mt * 16 + c) * 128 + s * 32 + q * 8), eb[s], o);
    f32x4_t r;
#pragma unroll
    for (int j = 0; j < 4; ++j) r[j] = fmaxf(o[j], 0.f);
    *reinterpret_cast<f32x4_t*>(out + (row0 + c) * 128 + mt * 16 + q * 4) = r;
  }
}

extern "C" void kernel_launch(void* const* d_in, const int* in_sizes, int n_in,
                              void* d_out, int out_size, void* d_ws,
                              size_t ws_size, hipStream_t stream) {
  const float* x = (const float*)d_in[0];
  const float* Win2E = (const float*)d_in[1];
  const float* WI2E = (const float*)d_in[2];
  const float* WE2I = (const float*)d_in[3];
  const float* WE2Out = (const float*)d_in[4];
  const int* Tptr = (const int*)d_in[5];
  float* out = (float*)d_out;
  (void)n_in; (void)out_size; (void)d_ws; (void)ws_size;

  const int B = in_sizes[0] / 128;  // 131072
  dim3 grid(B / 128), block(THREADS);
  unet_fused<<<grid, block, 0, stream>>>(x, Win2E, WI2E, WE2I, WE2Out, Tptr,
                                         out);
}